// Round 10
// baseline (322.149 us; speedup 1.0000x reference)
//
#include <hip/hip_runtime.h>

#define Hh 128
#define Ww 160
#define Cc 1024
#define HWp (Hh*Ww)

typedef float f4 __attribute__((ext_vector_type(4)));
#define AS1 __attribute__((address_space(1)))
#define AS3 __attribute__((address_space(3)))

// ---------------------------------------------------------------------------
// DPP cross-lane helpers (VALU latency, no LDS/ds_bpermute). Proven R2-R8.
template<int CTRL>
__device__ __forceinline__ float dppMaxStage(float v) {
    int t = __builtin_amdgcn_update_dpp((int)0xFF800000, __float_as_int(v),
                                        CTRL, 0xF, 0xF, false);
    return fmaxf(v, __int_as_float(t));
}
__device__ __forceinline__ float waveMaxDpp(float v) {
    v = dppMaxStage<0x111>(v);   // row_shr:1
    v = dppMaxStage<0x112>(v);   // row_shr:2
    v = dppMaxStage<0x114>(v);   // row_shr:4
    v = dppMaxStage<0x118>(v);   // row_shr:8
    v = dppMaxStage<0x142>(v);   // row_bcast:15
    v = dppMaxStage<0x143>(v);   // row_bcast:31  -> lane63 = wave max
    return __int_as_float(__builtin_amdgcn_readlane(__float_as_int(v), 63));
}
__device__ __forceinline__ float dppRor1(float v) {  // lane l <- lane (l-1)&63
    return __int_as_float(__builtin_amdgcn_update_dpp(0, __float_as_int(v),
                                                      0x13C, 0xF, 0xF, false));
}
__device__ __forceinline__ float dppRol1(float v) {  // lane l <- lane (l+1)&63
    return __int_as_float(__builtin_amdgcn_update_dpp(0, __float_as_int(v),
                                                      0x134, 0xF, 0xF, false));
}

// ---------------------------------------------------------------------------
// Normalize guidance: g (20, H, W) -> kn tables, stride 8 (b128-friendly).
// dir 0,1 (H-scans): kn[(d*HW + t*H + s)*8 + j]   (per-column contiguous)
// dir 2,3 (W-scans): kn[(d*HW + s*W + t)*8 + j]   (per-row contiguous)
__global__ __launch_bounds__(256) void norm_g(const float* __restrict__ g,
                                              float* __restrict__ kn)
{
    int p = blockIdx.x * blockDim.x + threadIdx.x;
    if (p >= HWp) return;
    int s = p / Ww, t = p - s * Ww;
    #pragma unroll
    for (int d = 0; d < 4; ++d) {
        float v[5]; float sum = 0.f;
        #pragma unroll
        for (int j = 0; j < 5; ++j) {
            v[j] = g[(size_t)(5 * d + j) * HWp + p];
            sum += fabsf(v[j]);
        }
        float inv = 1.f / fmaxf(sum, 1e-12f);
        size_t off = (d < 2) ? (((size_t)d * HWp + (size_t)t * Hh + s) * 8)
                             : (((size_t)d * HWp + (size_t)p) * 8);
        #pragma unroll
        for (int j = 0; j < 5; ++j) kn[off + j] = v[j] * inv;
        kn[off + 5] = 0.f; kn[off + 6] = 0.f; kn[off + 7] = 0.f;
    }
}

// ---------------------------------------------------------------------------
// Tiled transposes between (C, HW) and (HW, C).
__global__ __launch_bounds__(256) void transpose_in(const float* __restrict__ in,
                                                    float* __restrict__ out)
{
    __shared__ float tile[32][33];
    int p0 = blockIdx.x * 32, c0 = blockIdx.y * 32;
    int tx = threadIdx.x, ty = threadIdx.y;          // (32, 8)
    #pragma unroll
    for (int i = 0; i < 4; ++i)
        tile[ty + 8 * i][tx] = in[(size_t)(c0 + ty + 8 * i) * HWp + p0 + tx];
    __syncthreads();
    #pragma unroll
    for (int i = 0; i < 4; ++i)
        out[(size_t)(p0 + ty + 8 * i) * Cc + c0 + tx] = tile[tx][ty + 8 * i];
}

__global__ __launch_bounds__(256) void transpose_out(const float* __restrict__ Y,
                                                     float* __restrict__ out)
{
    __shared__ float tile[32][33];
    int c0 = blockIdx.x * 32, p0 = blockIdx.y * 32;
    int tx = threadIdx.x, ty = threadIdx.y;          // (32, 8)
    #pragma unroll
    for (int i = 0; i < 4; ++i)
        tile[ty + 8 * i][tx] = Y[(size_t)(p0 + ty + 8 * i) * Cc + c0 + tx];
    __syncthreads();
    #pragma unroll
    for (int i = 0; i < 4; ++i)
        out[(size_t)(c0 + ty + 8 * i) * HWp + p0 + tx] = tile[tx][ty + 8 * i];
}

// ---------------------------------------------------------------------------
// One directional scan pass on Y (H, W, C), in-place.
// 2 waves/block: wave 1 (producer) stages chunk c+1 via global_load_lds
// (direct global->LDS DMA: no VGPR round-trip, no load->ds_write dependency,
// all 64 x 1KB transfers of a chunk issued back-to-back); wave 0 (consumer)
// scans chunk c out of LDS and stores results straight to global.
// Split barrier per chunk: producer pre-waits vmcnt(0) (its DMA must be in
// LDS); consumer only lgkmcnt(0)+s_barrier -- its global stores (chunks <= c)
// need no ordering vs producer reads (chunk c+1), so the consumer's store
// queue never drains mid-kernel.
template<int NSTEPS, long STRIDE, long COLSTRIDE, bool FWD>
__global__ __launch_bounds__(128, 1) void scan_pass(float* __restrict__ Y,
                                                    const float* __restrict__ ktab)
{
    constexpr int CH = 16;                 // slices per chunk (64 KB)
    constexpr int NC = NSTEPS / CH;        // 8 (H) or 10 (W)
    __shared__ float xs[2][CH * Cc];       // 2 x 65536 B
    __shared__ float ks_raw[NSTEPS * 8 + 16];
    float* ks = ks_raw + 8;                // allow krow = -1 / NSTEPS overread
    const int tid = threadIdx.x;
    const int l = tid & 63;
    const int w = tid >> 6;                // 0 = consumer, 1 = producer
    const int loff = 4 * l;
    const long base = (long)blockIdx.x * COLSTRIDE;

    // stage k-table cooperatively (contiguous per chain by norm_g layout)
    const float* kt = ktab + (size_t)blockIdx.x * (size_t)(NSTEPS * 8);
    for (int i = tid; i < NSTEPS * 8; i += 128) ks[i] = kt[i];

    // producer: stage one chunk (16 slices = 64 x 1KB DMA) into buffer `buf`
    auto stage = [&](int c, int buf) {
        #pragma unroll
        for (int j = 0; j < CH; ++j) {
            const int step = c * CH + j;
            const long sl = FWD ? (long)step : (long)(NSTEPS - 1 - step);
            const float* src = Y + base + sl * STRIDE + loff;   // per-lane
            float* dst = &xs[buf][j * Cc];                      // wave-uniform
            #pragma unroll
            for (int q = 0; q < 4; ++q)
                __builtin_amdgcn_global_load_lds(
                    (const AS1 void*)(src + q * 256),
                    (AS3 void*)(dst + q * 256), 16, 0, 0);
        }
    };

    f4 prev[4];
    float pmax = 0.f;

    if (w == 1) {
        stage(0, 0);
        asm volatile("s_waitcnt vmcnt(0)" ::: "memory");
    }
    __syncthreads();   // ks table + chunk 0 ready

    for (int c = 0; c < NC; ++c) {
        if (w == 1) {
            if (c + 1 < NC) stage(c + 1, (c + 1) & 1);
            // DMA must be in LDS before the swap barrier
            asm volatile("s_waitcnt vmcnt(0)" ::: "memory");
        } else {
            const float* xb = xs[c & 1];
            int j0 = 0;
            if (c == 0) {
                // step 0: out = x (Y already holds it; nothing to store)
                #pragma unroll
                for (int q = 0; q < 4; ++q)
                    prev[q] = *(const f4*)&xb[q * 256 + loff];
                float mx = -3.4e38f;
                #pragma unroll
                for (int q = 0; q < 4; ++q)
                    mx = fmaxf(mx, fmaxf(fmaxf(prev[q].x, prev[q].y),
                                         fmaxf(prev[q].z, prev[q].w)));
                pmax = waveMaxDpp(mx);
                j0 = 1;
            }
            // x prefetch (1 slice ahead, within chunk) + k prefetch
            f4 xq[4];
            #pragma unroll
            for (int q = 0; q < 4; ++q)
                xq[q] = *(const f4*)&xb[j0 * Cc + q * 256 + loff];
            const int step0 = c * CH + j0;
            int krow = FWD ? step0 : (NSTEPS - 1 - step0);
            f4 pkv = *(const f4*)&ks[krow * 8];
            float pk4 = ks[krow * 8 + 4];

            #pragma unroll 4
            for (int j = j0; j < CH; ++j) {
                const int step = c * CH + j;
                const float k0 = pkv.x, k1 = pkv.y, k2 = pkv.z, k3 = pkv.w,
                            k4 = pk4;
                const int nk = FWD ? (step + 1) : (NSTEPS - 2 - step);
                pkv = *(const f4*)&ks[nk * 8];
                pk4 = ks[nk * 8 + 4];

                f4 xc[4];
                #pragma unroll
                for (int q = 0; q < 4; ++q) xc[q] = xq[q];
                if (j + 1 < CH) {
                    #pragma unroll
                    for (int q = 0; q < 4; ++q)
                        xq[q] = *(const f4*)&xb[(j + 1) * Cc + q * 256 + loff];
                }

                float A[4], B[4];
                #pragma unroll
                for (int q = 0; q < 4; ++q) {
                    A[q] = dppRor1(prev[q].w);   // lane l: prev.w @ (l-1)&63
                    B[q] = dppRol1(prev[q].x);   // lane l: prev.x @ (l+1)&63
                }
                f4 pt[4]; float m = -3.4e38f;
                #pragma unroll
                for (int q = 0; q < 4; ++q) {
                    float pm0 = (l > 0)  ? A[q] : (q > 0 ? A[q - 1] : 0.f);
                    float pp3 = (l < 63) ? B[q] : (q < 3 ? B[q + 1] : 0.f);
                    f4 p = prev[q], x = xc[q];
                    pt[q].x = k0 * x.x + k1 * p.x + k2 * pm0 + k3 * p.y;
                    pt[q].y = k0 * x.y + k1 * p.y + k2 * p.x + k3 * p.z;
                    pt[q].z = k0 * x.z + k1 * p.z + k2 * p.y + k3 * p.w;
                    pt[q].w = k0 * x.w + k1 * p.w + k2 * p.z + k3 * pp3;
                    m = fmaxf(m, fmaxf(fmaxf(pt[q].x, pt[q].y),
                                       fmaxf(pt[q].z, pt[q].w)));
                }
                float R = waveMaxDpp(m);
                #pragma unroll
                for (int q = 0; q < 4; ++q) {
                    prev[q].x = fmaf(k4, pmax, pt[q].x);
                    prev[q].y = fmaf(k4, pmax, pt[q].y);
                    prev[q].z = fmaf(k4, pmax, pt[q].z);
                    prev[q].w = fmaf(k4, pmax, pt[q].w);
                }
                const long sl = FWD ? (long)step : (long)(NSTEPS - 1 - step);
                float* dst = Y + base + sl * STRIDE + loff;
                *(f4*)(dst + 0)   = prev[0];
                *(f4*)(dst + 256) = prev[1];
                *(f4*)(dst + 512) = prev[2];
                *(f4*)(dst + 768) = prev[3];
                pmax = fmaf(k4, pmax, R);
            }
        }
        // buffer-swap barrier: LDS ops ordered; consumer stores NOT drained
        // (no in-kernel reader of them; endpgm drain is compiler-visible).
        asm volatile("s_waitcnt lgkmcnt(0)\n\ts_barrier" ::: "memory");
    }
}

// ---------------------------------------------------------------------------
extern "C" void kernel_launch(void* const* d_in, const int* in_sizes, int n_in,
                              void* d_out, int out_size, void* d_ws, size_t ws_size,
                              hipStream_t stream)
{
    const float* x = (const float*)d_in[0];   // (1, 32, 32, 128, 160) = (C,H,W)
    const float* g = (const float*)d_in[1];   // (1, 20, 128, 160)
    float* out = (float*)d_out;

    const size_t kn_bytes = (size_t)4 * HWp * 8 * sizeof(float);   // 2.6 MB
    const size_t y_bytes  = (size_t)Cc * HWp * sizeof(float);      // 84 MB
    if (ws_size < kn_bytes + y_bytes) return;

    float* kn = (float*)d_ws;
    float* Y  = (float*)((char*)d_ws + kn_bytes);

    // 1) normalize guidance into per-chain-contiguous tables (stride 8)
    norm_g<<<(HWp + 255) / 256, 256, 0, stream>>>(g, kn);

    // 2) transpose x (C,HW) -> Y (HW,C)
    transpose_in<<<dim3(HWp / 32, Cc / 32), dim3(32, 8), 0, stream>>>(x, Y);

    // 3) four in-place directional scans (2 waves/chain: DMA producer+consumer)
    scan_pass<Hh, (long)Ww * Cc, (long)Cc, true ><<<Ww, 128, 0, stream>>>(
        Y, kn + (size_t)0 * HWp * 8);
    scan_pass<Hh, (long)Ww * Cc, (long)Cc, false><<<Ww, 128, 0, stream>>>(
        Y, kn + (size_t)1 * HWp * 8);
    scan_pass<Ww, (long)Cc, (long)Ww * Cc, true ><<<Hh, 128, 0, stream>>>(
        Y, kn + (size_t)2 * HWp * 8);
    scan_pass<Ww, (long)Cc, (long)Ww * Cc, false><<<Hh, 128, 0, stream>>>(
        Y, kn + (size_t)3 * HWp * 8);

    // 4) transpose Y (HW,C) -> out (C,HW)
    transpose_out<<<dim3(Cc / 32, HWp / 32), dim3(32, 8), 0, stream>>>(Y, out);
}

// Round 11
// 309.126 us; speedup vs baseline: 1.0421x; 1.0421x over previous
//
#include <hip/hip_runtime.h>

#define Hh 128
#define Ww 160
#define Cc 1024
#define HWp (Hh*Ww)

typedef float f4 __attribute__((ext_vector_type(4)));
#define AS1 __attribute__((address_space(1)))
#define AS3 __attribute__((address_space(3)))

// ---------------------------------------------------------------------------
// DPP cross-lane helpers (VALU latency, no LDS/ds_bpermute). Proven R2-R9.
template<int CTRL>
__device__ __forceinline__ float dppMaxStage(float v) {
    int t = __builtin_amdgcn_update_dpp((int)0xFF800000, __float_as_int(v),
                                        CTRL, 0xF, 0xF, false);
    return fmaxf(v, __int_as_float(t));
}
__device__ __forceinline__ float waveMaxDpp(float v) {
    v = dppMaxStage<0x111>(v);   // row_shr:1
    v = dppMaxStage<0x112>(v);   // row_shr:2
    v = dppMaxStage<0x114>(v);   // row_shr:4
    v = dppMaxStage<0x118>(v);   // row_shr:8
    v = dppMaxStage<0x142>(v);   // row_bcast:15
    v = dppMaxStage<0x143>(v);   // row_bcast:31  -> lane63 = wave max
    return __int_as_float(__builtin_amdgcn_readlane(__float_as_int(v), 63));
}
__device__ __forceinline__ float dppRor1(float v) {  // lane l <- lane (l-1)&63
    return __int_as_float(__builtin_amdgcn_update_dpp(0, __float_as_int(v),
                                                      0x13C, 0xF, 0xF, false));
}
__device__ __forceinline__ float dppRol1(float v) {  // lane l <- lane (l+1)&63
    return __int_as_float(__builtin_amdgcn_update_dpp(0, __float_as_int(v),
                                                      0x134, 0xF, 0xF, false));
}

// ---------------------------------------------------------------------------
// Normalize guidance: g (20, H, W) -> kn tables, stride 8 (b128-friendly).
// dir 0,1 (H-scans): kn[(d*HW + t*H + s)*8 + j]   (per-column contiguous)
// dir 2,3 (W-scans): kn[(d*HW + s*W + t)*8 + j]   (per-row contiguous)
__global__ __launch_bounds__(256) void norm_g(const float* __restrict__ g,
                                              float* __restrict__ kn)
{
    int p = blockIdx.x * blockDim.x + threadIdx.x;
    if (p >= HWp) return;
    int s = p / Ww, t = p - s * Ww;
    #pragma unroll
    for (int d = 0; d < 4; ++d) {
        float v[5]; float sum = 0.f;
        #pragma unroll
        for (int j = 0; j < 5; ++j) {
            v[j] = g[(size_t)(5 * d + j) * HWp + p];
            sum += fabsf(v[j]);
        }
        float inv = 1.f / fmaxf(sum, 1e-12f);
        size_t off = (d < 2) ? (((size_t)d * HWp + (size_t)t * Hh + s) * 8)
                             : (((size_t)d * HWp + (size_t)p) * 8);
        #pragma unroll
        for (int j = 0; j < 5; ++j) kn[off + j] = v[j] * inv;
        kn[off + 5] = 0.f; kn[off + 6] = 0.f; kn[off + 7] = 0.f;
    }
}

// ---------------------------------------------------------------------------
// Tiled transposes between (C, HW) and (HW, C).
__global__ __launch_bounds__(256) void transpose_in(const float* __restrict__ in,
                                                    float* __restrict__ out)
{
    __shared__ float tile[32][33];
    int p0 = blockIdx.x * 32, c0 = blockIdx.y * 32;
    int tx = threadIdx.x, ty = threadIdx.y;          // (32, 8)
    #pragma unroll
    for (int i = 0; i < 4; ++i)
        tile[ty + 8 * i][tx] = in[(size_t)(c0 + ty + 8 * i) * HWp + p0 + tx];
    __syncthreads();
    #pragma unroll
    for (int i = 0; i < 4; ++i)
        out[(size_t)(p0 + ty + 8 * i) * Cc + c0 + tx] = tile[tx][ty + 8 * i];
}

__global__ __launch_bounds__(256) void transpose_out(const float* __restrict__ Y,
                                                     float* __restrict__ out)
{
    __shared__ float tile[32][33];
    int c0 = blockIdx.x * 32, p0 = blockIdx.y * 32;
    int tx = threadIdx.x, ty = threadIdx.y;          // (32, 8)
    #pragma unroll
    for (int i = 0; i < 4; ++i)
        tile[ty + 8 * i][tx] = Y[(size_t)(p0 + ty + 8 * i) * Cc + c0 + tx];
    __syncthreads();
    #pragma unroll
    for (int i = 0; i < 4; ++i)
        out[(size_t)(c0 + ty + 8 * i) * HWp + p0 + tx] = tile[tx][ty + 8 * i];
}

// ---------------------------------------------------------------------------
// One directional scan pass on Y (H, W, C), in-place.
// 5 waves/block (320 threads):
//   waves 1-4 (producers): stage chunk c+1 into the LDS double-buffer via
//     global_load_lds DMA. Wave p stages slices j = (p-1)+4m, m=0..3 (16 DMAs
//     each). FOUR independent per-wave vmcnt queues -> ~4x outstanding bytes.
//     R8/R9 diagnosis: ONE staging wave is latency-bound at ~7 GB/s/CU
//     (slices are 640 KB apart -> remote-XCD L2/HBM ~800cy; per-wave queue
//     depth caps in-flight bytes). Staging was the pipeline pacer.
//   wave 0 (consumer): scans chunk c from LDS; critical path pure-register
//     (DPP + FMA); stores results straight to global (never drained in-loop).
// Split barrier per chunk: producers pre-wait their own vmcnt(0); consumer
// waits lgkmcnt(0) only.
template<int NSTEPS, long STRIDE, long COLSTRIDE, bool FWD>
__global__ __launch_bounds__(320, 1) void scan_pass(float* __restrict__ Y,
                                                    const float* __restrict__ ktab)
{
    constexpr int CH = 16;                 // slices per chunk (64 KB)
    constexpr int NC = NSTEPS / CH;        // 8 (H) or 10 (W)
    __shared__ float xs[2][CH * Cc];       // 2 x 65536 B
    __shared__ float ks_raw[NSTEPS * 8 + 16];
    float* ks = ks_raw + 8;                // allow krow = -1 / NSTEPS overread
    const int tid = threadIdx.x;
    const int l = tid & 63;
    const int w = tid >> 6;                // 0 = consumer, 1..4 = producers
    const int loff = 4 * l;
    const long base = (long)blockIdx.x * COLSTRIDE;

    // stage k-table cooperatively (contiguous per chain by norm_g layout)
    const float* kt = ktab + (size_t)blockIdx.x * (size_t)(NSTEPS * 8);
    for (int i = tid; i < NSTEPS * 8; i += 320) ks[i] = kt[i];

    // producer wave p: stage its 4 slices of chunk c into buffer `buf`
    auto stage = [&](int c, int buf, int p) {
        #pragma unroll
        for (int m = 0; m < 4; ++m) {
            const int j = (p - 1) + 4 * m;
            const int step = c * CH + j;
            const long sl = FWD ? (long)step : (long)(NSTEPS - 1 - step);
            const float* src = Y + base + sl * STRIDE + loff;   // per-lane
            float* dst = &xs[buf][j * Cc];                      // wave-uniform
            #pragma unroll
            for (int q = 0; q < 4; ++q)
                __builtin_amdgcn_global_load_lds(
                    (const AS1 void*)(src + q * 256),
                    (AS3 void*)(dst + q * 256), 16, 0, 0);
        }
    };

    f4 prev[4];
    float pmax = 0.f;

    if (w >= 1) {
        stage(0, 0, w);
        asm volatile("s_waitcnt vmcnt(0)" ::: "memory");
    }
    // everyone: ks writes ordered, then barrier
    asm volatile("s_waitcnt lgkmcnt(0)\n\ts_barrier" ::: "memory");

    for (int c = 0; c < NC; ++c) {
        if (w >= 1) {
            if (c + 1 < NC) stage(c + 1, (c + 1) & 1, w);
            // this wave's DMAs must be in LDS before the swap barrier
            asm volatile("s_waitcnt vmcnt(0)" ::: "memory");
        } else {
            const float* xb = xs[c & 1];
            int j0 = 0;
            if (c == 0) {
                // step 0: out = x (Y already holds it; nothing to store)
                #pragma unroll
                for (int q = 0; q < 4; ++q)
                    prev[q] = *(const f4*)&xb[q * 256 + loff];
                float mx = -3.4e38f;
                #pragma unroll
                for (int q = 0; q < 4; ++q)
                    mx = fmaxf(mx, fmaxf(fmaxf(prev[q].x, prev[q].y),
                                         fmaxf(prev[q].z, prev[q].w)));
                pmax = waveMaxDpp(mx);
                j0 = 1;
            }
            // x prefetch (1 slice ahead, within chunk) + k prefetch
            f4 xq[4];
            #pragma unroll
            for (int q = 0; q < 4; ++q)
                xq[q] = *(const f4*)&xb[j0 * Cc + q * 256 + loff];
            const int step0 = c * CH + j0;
            int krow = FWD ? step0 : (NSTEPS - 1 - step0);
            f4 pkv = *(const f4*)&ks[krow * 8];
            float pk4 = ks[krow * 8 + 4];

            #pragma unroll 4
            for (int j = j0; j < CH; ++j) {
                const int step = c * CH + j;
                const float k0 = pkv.x, k1 = pkv.y, k2 = pkv.z, k3 = pkv.w,
                            k4 = pk4;
                const int nk = FWD ? (step + 1) : (NSTEPS - 2 - step);
                pkv = *(const f4*)&ks[nk * 8];
                pk4 = ks[nk * 8 + 4];

                f4 xc[4];
                #pragma unroll
                for (int q = 0; q < 4; ++q) xc[q] = xq[q];
                if (j + 1 < CH) {
                    #pragma unroll
                    for (int q = 0; q < 4; ++q)
                        xq[q] = *(const f4*)&xb[(j + 1) * Cc + q * 256 + loff];
                }

                float A[4], B[4];
                #pragma unroll
                for (int q = 0; q < 4; ++q) {
                    A[q] = dppRor1(prev[q].w);   // lane l: prev.w @ (l-1)&63
                    B[q] = dppRol1(prev[q].x);   // lane l: prev.x @ (l+1)&63
                }
                f4 pt[4]; float m = -3.4e38f;
                #pragma unroll
                for (int q = 0; q < 4; ++q) {
                    float pm0 = (l > 0)  ? A[q] : (q > 0 ? A[q - 1] : 0.f);
                    float pp3 = (l < 63) ? B[q] : (q < 3 ? B[q + 1] : 0.f);
                    f4 p = prev[q], x = xc[q];
                    pt[q].x = k0 * x.x + k1 * p.x + k2 * pm0 + k3 * p.y;
                    pt[q].y = k0 * x.y + k1 * p.y + k2 * p.x + k3 * p.z;
                    pt[q].z = k0 * x.z + k1 * p.z + k2 * p.y + k3 * p.w;
                    pt[q].w = k0 * x.w + k1 * p.w + k2 * p.z + k3 * pp3;
                    m = fmaxf(m, fmaxf(fmaxf(pt[q].x, pt[q].y),
                                       fmaxf(pt[q].z, pt[q].w)));
                }
                float R = waveMaxDpp(m);
                #pragma unroll
                for (int q = 0; q < 4; ++q) {
                    prev[q].x = fmaf(k4, pmax, pt[q].x);
                    prev[q].y = fmaf(k4, pmax, pt[q].y);
                    prev[q].z = fmaf(k4, pmax, pt[q].z);
                    prev[q].w = fmaf(k4, pmax, pt[q].w);
                }
                const long sl = FWD ? (long)step : (long)(NSTEPS - 1 - step);
                float* dst = Y + base + sl * STRIDE + loff;
                *(f4*)(dst + 0)   = prev[0];
                *(f4*)(dst + 256) = prev[1];
                *(f4*)(dst + 512) = prev[2];
                *(f4*)(dst + 768) = prev[3];
                pmax = fmaf(k4, pmax, R);
            }
        }
        // buffer-swap barrier: LDS ops ordered; consumer stores NOT drained.
        asm volatile("s_waitcnt lgkmcnt(0)\n\ts_barrier" ::: "memory");
    }
}

// ---------------------------------------------------------------------------
extern "C" void kernel_launch(void* const* d_in, const int* in_sizes, int n_in,
                              void* d_out, int out_size, void* d_ws, size_t ws_size,
                              hipStream_t stream)
{
    const float* x = (const float*)d_in[0];   // (1, 32, 32, 128, 160) = (C,H,W)
    const float* g = (const float*)d_in[1];   // (1, 20, 128, 160)
    float* out = (float*)d_out;

    const size_t kn_bytes = (size_t)4 * HWp * 8 * sizeof(float);   // 2.6 MB
    const size_t y_bytes  = (size_t)Cc * HWp * sizeof(float);      // 84 MB
    if (ws_size < kn_bytes + y_bytes) return;

    float* kn = (float*)d_ws;
    float* Y  = (float*)((char*)d_ws + kn_bytes);

    // 1) normalize guidance into per-chain-contiguous tables (stride 8)
    norm_g<<<(HWp + 255) / 256, 256, 0, stream>>>(g, kn);

    // 2) transpose x (C,HW) -> Y (HW,C)
    transpose_in<<<dim3(HWp / 32, Cc / 32), dim3(32, 8), 0, stream>>>(x, Y);

    // 3) four in-place directional scans (4 DMA-producer waves + 1 consumer)
    scan_pass<Hh, (long)Ww * Cc, (long)Cc, true ><<<Ww, 320, 0, stream>>>(
        Y, kn + (size_t)0 * HWp * 8);
    scan_pass<Hh, (long)Ww * Cc, (long)Cc, false><<<Ww, 320, 0, stream>>>(
        Y, kn + (size_t)1 * HWp * 8);
    scan_pass<Ww, (long)Cc, (long)Ww * Cc, true ><<<Hh, 320, 0, stream>>>(
        Y, kn + (size_t)2 * HWp * 8);
    scan_pass<Ww, (long)Cc, (long)Ww * Cc, false><<<Hh, 320, 0, stream>>>(
        Y, kn + (size_t)3 * HWp * 8);

    // 4) transpose Y (HW,C) -> out (C,HW)
    transpose_out<<<dim3(Cc / 32, HWp / 32), dim3(32, 8), 0, stream>>>(Y, out);
}

// Round 12
// 291.263 us; speedup vs baseline: 1.1060x; 1.0613x over previous
//
#include <hip/hip_runtime.h>

#define Hh 128
#define Ww 160
#define Cc 1024
#define HWp (Hh*Ww)

typedef float f4 __attribute__((ext_vector_type(4)));

// ---------------------------------------------------------------------------
// DPP cross-lane helpers (VALU latency, no LDS/ds_bpermute). Proven R2-R10.
template<int CTRL>
__device__ __forceinline__ float dppMaxStage(float v) {
    int t = __builtin_amdgcn_update_dpp((int)0xFF800000, __float_as_int(v),
                                        CTRL, 0xF, 0xF, false);
    return fmaxf(v, __int_as_float(t));
}
__device__ __forceinline__ float waveMaxDpp(float v) {
    v = dppMaxStage<0x111>(v);   // row_shr:1
    v = dppMaxStage<0x112>(v);   // row_shr:2
    v = dppMaxStage<0x114>(v);   // row_shr:4
    v = dppMaxStage<0x118>(v);   // row_shr:8
    v = dppMaxStage<0x142>(v);   // row_bcast:15
    v = dppMaxStage<0x143>(v);   // row_bcast:31  -> lane63 = wave max
    return __int_as_float(__builtin_amdgcn_readlane(__float_as_int(v), 63));
}
__device__ __forceinline__ float dppRor1(float v) {  // lane l <- lane (l-1)&63
    return __int_as_float(__builtin_amdgcn_update_dpp(0, __float_as_int(v),
                                                      0x13C, 0xF, 0xF, false));
}
__device__ __forceinline__ float dppRol1(float v) {  // lane l <- lane (l+1)&63
    return __int_as_float(__builtin_amdgcn_update_dpp(0, __float_as_int(v),
                                                      0x134, 0xF, 0xF, false));
}

// ---------------------------------------------------------------------------
// Normalize guidance: g (20, H, W) -> kn tables, stride 8 (b128-friendly).
// dir 0,1 (H-scans): kn[(d*HW + t*H + s)*8 + j]   (per-column contiguous)
// dir 2,3 (W-scans): kn[(d*HW + s*W + t)*8 + j]   (per-row contiguous)
__global__ __launch_bounds__(256) void norm_g(const float* __restrict__ g,
                                              float* __restrict__ kn)
{
    int p = blockIdx.x * blockDim.x + threadIdx.x;
    if (p >= HWp) return;
    int s = p / Ww, t = p - s * Ww;
    #pragma unroll
    for (int d = 0; d < 4; ++d) {
        float v[5]; float sum = 0.f;
        #pragma unroll
        for (int j = 0; j < 5; ++j) {
            v[j] = g[(size_t)(5 * d + j) * HWp + p];
            sum += fabsf(v[j]);
        }
        float inv = 1.f / fmaxf(sum, 1e-12f);
        size_t off = (d < 2) ? (((size_t)d * HWp + (size_t)t * Hh + s) * 8)
                             : (((size_t)d * HWp + (size_t)p) * 8);
        #pragma unroll
        for (int j = 0; j < 5; ++j) kn[off + j] = v[j] * inv;
        kn[off + 5] = 0.f; kn[off + 6] = 0.f; kn[off + 7] = 0.f;
    }
}

// ---------------------------------------------------------------------------
// Tiled transposes between (C, HW) and (HW, C).
__global__ __launch_bounds__(256) void transpose_in(const float* __restrict__ in,
                                                    float* __restrict__ out)
{
    __shared__ float tile[32][33];
    int p0 = blockIdx.x * 32, c0 = blockIdx.y * 32;
    int tx = threadIdx.x, ty = threadIdx.y;          // (32, 8)
    #pragma unroll
    for (int i = 0; i < 4; ++i)
        tile[ty + 8 * i][tx] = in[(size_t)(c0 + ty + 8 * i) * HWp + p0 + tx];
    __syncthreads();
    #pragma unroll
    for (int i = 0; i < 4; ++i)
        out[(size_t)(p0 + ty + 8 * i) * Cc + c0 + tx] = tile[tx][ty + 8 * i];
}

__global__ __launch_bounds__(256) void transpose_out(const float* __restrict__ Y,
                                                     float* __restrict__ out)
{
    __shared__ float tile[32][33];
    int c0 = blockIdx.x * 32, p0 = blockIdx.y * 32;
    int tx = threadIdx.x, ty = threadIdx.y;          // (32, 8)
    #pragma unroll
    for (int i = 0; i < 4; ++i)
        tile[ty + 8 * i][tx] = Y[(size_t)(p0 + ty + 8 * i) * Cc + c0 + tx];
    __syncthreads();
    #pragma unroll
    for (int i = 0; i < 4; ++i)
        out[(size_t)(c0 + ty + 8 * i) * HWp + p0 + tx] = tile[tx][ty + 8 * i];
}

// ---------------------------------------------------------------------------
// One directional scan pass on Y (H, W, C), in-place.
// 9 waves/block (576 threads):
//   waves 1-8 (producers): stage chunk c+1 (16 slices = 64 KB) into the LDS
//     double-buffer via PLAIN VGPR loads + ds_write. Each wave: 2 slices,
//     written as 8 independent named f4 loads issued back-to-back, THEN
//     8 ds_writes -> compiler emits progressive vmcnt(7..0), keeping ~8 KB
//     in flight per wave x 8 waves ~= 64 KB/CU outstanding.
//     (R8-R10 diagnosis: staging was per-CU memory-parallelism-bound at
//     ~7 GB/s -- 1-4 waves / DMA never scaled in-flight depth. Effective BW
//     = in-flight bytes / latency; this structure maximizes in-flight.)
//   wave 0 (consumer): scans chunk c from LDS; critical path pure-register
//     (DPP + FMA); stores results straight to global (never drained in-loop).
// Barrier per chunk: s_waitcnt lgkmcnt(0) + s_barrier for ALL waves (covers
// producers' ds_writes and consumer's ds_reads; consumer's global stores are
// compiler-visible and only drained at endpgm).
template<int NSTEPS, long STRIDE, long COLSTRIDE, bool FWD>
__global__ __launch_bounds__(576, 1) void scan_pass(float* __restrict__ Y,
                                                    const float* __restrict__ ktab)
{
    constexpr int CH = 16;                 // slices per chunk (64 KB)
    constexpr int NC = NSTEPS / CH;        // 8 (H) or 10 (W)
    __shared__ float xs[2][CH * Cc];       // 2 x 65536 B
    __shared__ float ks_raw[NSTEPS * 8 + 16];
    float* ks = ks_raw + 8;                // allow krow = -1 / NSTEPS overread
    const int tid = threadIdx.x;
    const int l = tid & 63;
    const int w = tid >> 6;                // 0 = consumer, 1..8 = producers
    const int loff = 4 * l;
    const long base = (long)blockIdx.x * COLSTRIDE;

    // stage k-table cooperatively (contiguous per chain by norm_g layout)
    const float* kt = ktab + (size_t)blockIdx.x * (size_t)(NSTEPS * 8);
    for (int i = tid; i < NSTEPS * 8; i += 576) ks[i] = kt[i];

    // producer wave p (1..8): stage slices 2(p-1), 2(p-1)+1 of chunk c.
    // 8 loads issued first (deep in-flight), then 8 ds_writes.
    auto stage = [&](int c, int buf, int p) {
        const int j0 = 2 * (p - 1);
        const int s0 = c * CH + j0;
        const long sl0 = FWD ? (long)s0 : (long)(NSTEPS - 1 - s0);
        const long sl1 = FWD ? (long)(s0 + 1) : (long)(NSTEPS - 2 - s0);
        const float* a = Y + base + sl0 * STRIDE + loff;
        const float* b = Y + base + sl1 * STRIDE + loff;
        f4 t0 = *(const f4*)(a + 0),   t1 = *(const f4*)(a + 256);
        f4 t2 = *(const f4*)(a + 512), t3 = *(const f4*)(a + 768);
        f4 u0 = *(const f4*)(b + 0),   u1 = *(const f4*)(b + 256);
        f4 u2 = *(const f4*)(b + 512), u3 = *(const f4*)(b + 768);
        float* da = &xs[buf][j0 * Cc + loff];
        float* db = &xs[buf][(j0 + 1) * Cc + loff];
        *(f4*)(da + 0)   = t0; *(f4*)(da + 256) = t1;
        *(f4*)(da + 512) = t2; *(f4*)(da + 768) = t3;
        *(f4*)(db + 0)   = u0; *(f4*)(db + 256) = u1;
        *(f4*)(db + 512) = u2; *(f4*)(db + 768) = u3;
    };

    f4 prev[4];
    float pmax = 0.f;

    if (w >= 1) stage(0, 0, w);
    // everyone: ks + chunk-0 ds_writes ordered, then barrier
    asm volatile("s_waitcnt lgkmcnt(0)\n\ts_barrier" ::: "memory");

    for (int c = 0; c < NC; ++c) {
        if (w >= 1) {
            if (c + 1 < NC) stage(c + 1, (c + 1) & 1, w);
        } else {
            const float* xb = xs[c & 1];
            int j0 = 0;
            if (c == 0) {
                // step 0: out = x (Y already holds it; nothing to store)
                #pragma unroll
                for (int q = 0; q < 4; ++q)
                    prev[q] = *(const f4*)&xb[q * 256 + loff];
                float mx = -3.4e38f;
                #pragma unroll
                for (int q = 0; q < 4; ++q)
                    mx = fmaxf(mx, fmaxf(fmaxf(prev[q].x, prev[q].y),
                                         fmaxf(prev[q].z, prev[q].w)));
                pmax = waveMaxDpp(mx);
                j0 = 1;
            }
            // x prefetch (1 slice ahead, within chunk) + k prefetch
            f4 xq[4];
            #pragma unroll
            for (int q = 0; q < 4; ++q)
                xq[q] = *(const f4*)&xb[j0 * Cc + q * 256 + loff];
            const int step0 = c * CH + j0;
            int krow = FWD ? step0 : (NSTEPS - 1 - step0);
            f4 pkv = *(const f4*)&ks[krow * 8];
            float pk4 = ks[krow * 8 + 4];

            #pragma unroll 4
            for (int j = j0; j < CH; ++j) {
                const int step = c * CH + j;
                const float k0 = pkv.x, k1 = pkv.y, k2 = pkv.z, k3 = pkv.w,
                            k4 = pk4;
                const int nk = FWD ? (step + 1) : (NSTEPS - 2 - step);
                pkv = *(const f4*)&ks[nk * 8];
                pk4 = ks[nk * 8 + 4];

                f4 xc[4];
                #pragma unroll
                for (int q = 0; q < 4; ++q) xc[q] = xq[q];
                if (j + 1 < CH) {
                    #pragma unroll
                    for (int q = 0; q < 4; ++q)
                        xq[q] = *(const f4*)&xb[(j + 1) * Cc + q * 256 + loff];
                }

                float A[4], B[4];
                #pragma unroll
                for (int q = 0; q < 4; ++q) {
                    A[q] = dppRor1(prev[q].w);   // lane l: prev.w @ (l-1)&63
                    B[q] = dppRol1(prev[q].x);   // lane l: prev.x @ (l+1)&63
                }
                f4 pt[4]; float m = -3.4e38f;
                #pragma unroll
                for (int q = 0; q < 4; ++q) {
                    float pm0 = (l > 0)  ? A[q] : (q > 0 ? A[q - 1] : 0.f);
                    float pp3 = (l < 63) ? B[q] : (q < 3 ? B[q + 1] : 0.f);
                    f4 p = prev[q], x = xc[q];
                    pt[q].x = k0 * x.x + k1 * p.x + k2 * pm0 + k3 * p.y;
                    pt[q].y = k0 * x.y + k1 * p.y + k2 * p.x + k3 * p.z;
                    pt[q].z = k0 * x.z + k1 * p.z + k2 * p.y + k3 * p.w;
                    pt[q].w = k0 * x.w + k1 * p.w + k2 * p.z + k3 * pp3;
                    m = fmaxf(m, fmaxf(fmaxf(pt[q].x, pt[q].y),
                                       fmaxf(pt[q].z, pt[q].w)));
                }
                float R = waveMaxDpp(m);
                #pragma unroll
                for (int q = 0; q < 4; ++q) {
                    prev[q].x = fmaf(k4, pmax, pt[q].x);
                    prev[q].y = fmaf(k4, pmax, pt[q].y);
                    prev[q].z = fmaf(k4, pmax, pt[q].z);
                    prev[q].w = fmaf(k4, pmax, pt[q].w);
                }
                const long sl = FWD ? (long)step : (long)(NSTEPS - 1 - step);
                float* dst = Y + base + sl * STRIDE + loff;
                *(f4*)(dst + 0)   = prev[0];
                *(f4*)(dst + 256) = prev[1];
                *(f4*)(dst + 512) = prev[2];
                *(f4*)(dst + 768) = prev[3];
                pmax = fmaf(k4, pmax, R);
            }
        }
        // buffer-swap barrier: all LDS ops ordered; consumer stores NOT
        // drained (compiler-visible; drained once at endpgm).
        asm volatile("s_waitcnt lgkmcnt(0)\n\ts_barrier" ::: "memory");
    }
}

// ---------------------------------------------------------------------------
extern "C" void kernel_launch(void* const* d_in, const int* in_sizes, int n_in,
                              void* d_out, int out_size, void* d_ws, size_t ws_size,
                              hipStream_t stream)
{
    const float* x = (const float*)d_in[0];   // (1, 32, 32, 128, 160) = (C,H,W)
    const float* g = (const float*)d_in[1];   // (1, 20, 128, 160)
    float* out = (float*)d_out;

    const size_t kn_bytes = (size_t)4 * HWp * 8 * sizeof(float);   // 2.6 MB
    const size_t y_bytes  = (size_t)Cc * HWp * sizeof(float);      // 84 MB
    if (ws_size < kn_bytes + y_bytes) return;

    float* kn = (float*)d_ws;
    float* Y  = (float*)((char*)d_ws + kn_bytes);

    // 1) normalize guidance into per-chain-contiguous tables (stride 8)
    norm_g<<<(HWp + 255) / 256, 256, 0, stream>>>(g, kn);

    // 2) transpose x (C,HW) -> Y (HW,C)
    transpose_in<<<dim3(HWp / 32, Cc / 32), dim3(32, 8), 0, stream>>>(x, Y);

    // 3) four in-place directional scans (8 load/ds_write producers + 1 consumer)
    scan_pass<Hh, (long)Ww * Cc, (long)Cc, true ><<<Ww, 576, 0, stream>>>(
        Y, kn + (size_t)0 * HWp * 8);
    scan_pass<Hh, (long)Ww * Cc, (long)Cc, false><<<Ww, 576, 0, stream>>>(
        Y, kn + (size_t)1 * HWp * 8);
    scan_pass<Ww, (long)Cc, (long)Ww * Cc, true ><<<Hh, 576, 0, stream>>>(
        Y, kn + (size_t)2 * HWp * 8);
    scan_pass<Ww, (long)Cc, (long)Ww * Cc, false><<<Hh, 576, 0, stream>>>(
        Y, kn + (size_t)3 * HWp * 8);

    // 4) transpose Y (HW,C) -> out (C,HW)
    transpose_out<<<dim3(Cc / 32, HWp / 32), dim3(32, 8), 0, stream>>>(Y, out);
}